// Round 4
// baseline (12.320 us; speedup 1.0000x reference)
//
#include <hip/hip_runtime.h>
#include <hip/hip_bf16.h>

#define BB 8
#define TT 2048
#define FF 64
#define LL 48
#define TB 32            // tokens per block
#define RE (TB + LL)     // extended He rows: t0-48 .. t0+31  (= 80)
#define NW 8
#define NT (NW * 64)

typedef __attribute__((ext_vector_type(8))) short bf16x8;   // MFMA A/B frag (8 bf16)
typedef __attribute__((ext_vector_type(4))) float f32x4;    // MFMA C/D frag

// LDS layout (bytes). 2D tiles: row stride = chunks*16B, XOR-swizzled chunk ^= (row&7).
#define HE_HI 0          // He_ext hi [80][64] bf16, 8 chunks/row (A-op: rows=r_ext, k=f)
#define HE_LO 10240      // He_ext lo
#define WT_HI 20480      // W^T hi [64][64] bf16 (B-op Q: rows=g, k=f)      [dead after phase 2]
#define WT_LO 28672      // W^T lo
#define QQ_HI 36864      // Q hi [32][64] bf16   (B-op S: rows=tok, k=g)    [dead after phase 3]
#define QQ_LO 40960      // Q lo
// aliases, live from phase 4 on:
#define HET   20480      // He_extT [64][128] bf16, 16 chunks/row (B-op ctx: rows=f, k=r_ext; chunks>9 unread)
#define PT    36864      // P^T     [32][128] bf16, 16 chunks/row (A-op ctx: rows=tok, k=r_ext)
#define RED   45056      // [32 tok][4 part][m,sum] f32 = 1024 B
#define SMEM_BYTES 46080

__device__ __forceinline__ unsigned short f2b(float x) {    // fp32 -> bf16 RNE
    unsigned int u = __builtin_bit_cast(unsigned int, x);
    return (unsigned short)((u + 0x7FFFu + ((u >> 16) & 1u)) >> 16);
}
__device__ __forceinline__ float b2f(unsigned short h) {
    return __builtin_bit_cast(float, (unsigned int)h << 16);
}

__global__ __launch_bounds__(NT, 2)
void ContextBlock_kernel(const float* __restrict__ he,
                         const float* __restrict__ Wm,
                         const float* __restrict__ bias,
                         float* __restrict__ out)
{
    __shared__ __align__(16) unsigned char smem[SMEM_BYTES];

    const int tid  = threadIdx.x;
    const int wave = tid >> 6;
    const int lane = tid & 63;
    const int bb   = blockIdx.y;
    const int t0   = blockIdx.x * TB;

    const float* heb = he + (size_t)bb * TT * FF;

    // ---- phase 1: stage He_ext (hi/lo, swizzled) + W^T (hi/lo) ----
    const float4* he4 = (const float4*)heb;
    for (int e = tid; e < RE * 16; e += NT) {               // 80 rows x 16 float4-chunks
        int r = e >> 4, c4 = e & 15;
        int g = t0 - LL + r; g = g < 0 ? 0 : g;             // clamp = reference's clip(rel,0,..)
        float4 v = he4[g * 16 + c4];
        unsigned short h0 = f2b(v.x), h1 = f2b(v.y), h2 = f2b(v.z), h3 = f2b(v.w);
        unsigned short l0 = f2b(v.x - b2f(h0)), l1 = f2b(v.y - b2f(h1));
        unsigned short l2 = f2b(v.z - b2f(h2)), l3 = f2b(v.w - b2f(h3));
        unsigned long long pkh = (unsigned long long)h0 | ((unsigned long long)h1 << 16)
                               | ((unsigned long long)h2 << 32) | ((unsigned long long)h3 << 48);
        unsigned long long pkl = (unsigned long long)l0 | ((unsigned long long)l1 << 16)
                               | ((unsigned long long)l2 << 32) | ((unsigned long long)l3 << 48);
        int off = r * 128 + ((((c4 >> 1) ^ (r & 7)) << 4)) + ((c4 & 1) << 3);
        *(unsigned long long*)(smem + HE_HI + off) = pkh;
        *(unsigned long long*)(smem + HE_LO + off) = pkl;
    }
    const float4* w4 = (const float4*)Wm;
    for (int e = tid; e < 1024; e += NT) {                  // W: 64x64 = 1024 float4-chunks
        int f = e >> 4, g4 = e & 15;
        float4 v = w4[e];
        float vv[4] = {v.x, v.y, v.z, v.w};
        #pragma unroll
        for (int i = 0; i < 4; ++i) {
            int g = g4 * 4 + i;
            unsigned short hi = f2b(vv[i]);
            unsigned short lo = f2b(vv[i] - b2f(hi));
            int off = g * 128 + ((((f >> 3) ^ (g & 7)) << 4)) + ((f & 7) << 1);
            *(unsigned short*)(smem + WT_HI + off) = hi;
            *(unsigned short*)(smem + WT_LO + off) = lo;
        }
    }
    __syncthreads();

    const int l15 = lane & 15;
    const int lhi = lane >> 4;

    // ---- phase 2: Q = He*W + b, split-bf16 (1 tile/wave) -> Q hi/lo ----
    {
        int mt = wave >> 2, nt = wave & 3;
        f32x4 acc = (f32x4){0.f, 0.f, 0.f, 0.f};
        int arow = LL + mt * 16 + l15;                      // He row of token
        int colg = nt * 16 + l15;
        #pragma unroll
        for (int kf = 0; kf < 2; ++kf) {
            int chunk = 4 * kf + lhi;
            int offA = arow * 128 + ((chunk ^ (arow & 7)) << 4);
            int offB = colg * 128 + ((chunk ^ (colg & 7)) << 4);
            bf16x8 ah = *(const bf16x8*)(smem + HE_HI + offA);
            bf16x8 al = *(const bf16x8*)(smem + HE_LO + offA);
            bf16x8 bh = *(const bf16x8*)(smem + WT_HI + offB);
            bf16x8 bl = *(const bf16x8*)(smem + WT_LO + offB);
            acc = __builtin_amdgcn_mfma_f32_16x16x32_bf16(ah, bh, acc, 0, 0, 0);
            acc = __builtin_amdgcn_mfma_f32_16x16x32_bf16(ah, bl, acc, 0, 0, 0);
            acc = __builtin_amdgcn_mfma_f32_16x16x32_bf16(al, bh, acc, 0, 0, 0);
        }
        float bv = bias[colg];
        #pragma unroll
        for (int i = 0; i < 4; ++i) {                       // C: row=tok=(lane>>4)*4+i, col=g
            int tok = mt * 16 + lhi * 4 + i;
            float qv = acc[i] + bv;
            unsigned short hi = f2b(qv);
            unsigned short lo = f2b(qv - b2f(hi));
            int off = tok * 128 + ((((colg >> 3) ^ (tok & 7)) << 4)) + ((colg & 7) << 1);
            *(unsigned short*)(smem + QQ_HI + off) = hi;
            *(unsigned short*)(smem + QQ_LO + off) = lo;
        }
    }
    __syncthreads();

    // ---- phase 3: scores S = He_ext * Q^T (split-bf16, 1 band-tile/wave) + partial softmax ----
    const int ct = wave >> 2, uu = wave & 3;
    const int rt = ct + uu;                                 // row-tile covering r_ext band of col-tile ct
    const int tok = ct * 16 + l15;                          // this lane's token column (local)
    f32x4 sc;
    {
        f32x4 acc = (f32x4){0.f, 0.f, 0.f, 0.f};
        int arow = rt * 16 + l15;
        #pragma unroll
        for (int kf = 0; kf < 2; ++kf) {
            int chunk = 4 * kf + lhi;
            int offA = arow * 128 + ((chunk ^ (arow & 7)) << 4);
            int offB = tok * 128 + ((chunk ^ (tok & 7)) << 4);
            bf16x8 ah = *(const bf16x8*)(smem + HE_HI + offA);
            bf16x8 al = *(const bf16x8*)(smem + HE_LO + offA);
            bf16x8 bh = *(const bf16x8*)(smem + QQ_HI + offB);
            bf16x8 bl = *(const bf16x8*)(smem + QQ_LO + offB);
            acc = __builtin_amdgcn_mfma_f32_16x16x32_bf16(ah, bh, acc, 0, 0, 0);
            acc = __builtin_amdgcn_mfma_f32_16x16x32_bf16(ah, bl, acc, 0, 0, 0);
            acc = __builtin_amdgcn_mfma_f32_16x16x32_bf16(al, bh, acc, 0, 0, 0);
        }
        sc = acc;
    }
    // mask: element (r_ext = 16rt + 4*lhi + i, token col = tok); partial max/sum over this tile
    float m = -1e30f;
    #pragma unroll
    for (int i = 0; i < 4; ++i) {
        int r_ext = rt * 16 + lhi * 4 + i;
        int l = r_ext - tok;
        bool valid = (t0 == 0 && tok == 0) ? (r_ext == LL - 1)
                                           : (l >= 0 && l < LL && (t0 + r_ext) >= LL);
        float s = valid ? sc[i] : -1e30f;
        sc[i] = s;
        m = fmaxf(m, s);
    }
    m = fmaxf(m, __shfl_xor(m, 16));
    m = fmaxf(m, __shfl_xor(m, 32));                        // column max over tile rows
    float sum = 0.f;
    #pragma unroll
    for (int i = 0; i < 4; ++i)
        sum += __expf(sc[i] - m);                           // all-invalid partial: m=-1e30, sum=0
    sum += __shfl_xor(sum, 16);
    sum += __shfl_xor(sum, 32);
    if (lane < 16)
        *(float2*)(smem + RED + tok * 32 + uu * 8) = make_float2(m, sum);
    __syncthreads();

    // ---- phase 4: combine 4 partials -> P^T; build He_extT from He_hi (WT/QQ now dead) ----
    {
        float M = -1e30f;
        float2 p[4];
        #pragma unroll
        for (int u = 0; u < 4; ++u) {
            p[u] = *(const float2*)(smem + RED + tok * 32 + u * 8);
            M = fmaxf(M, p[u].x);
        }
        float T = 0.f;
        #pragma unroll
        for (int u = 0; u < 4; ++u)
            T += p[u].y * __expf(p[u].x - M);
        float invT = 1.0f / T;
        int rbase = rt * 16 + lhi * 4;                      // 4 consecutive r_ext of this wave's tile
        unsigned short w0 = f2b(__expf(sc[0] - M) * invT);
        unsigned short w1 = f2b(__expf(sc[1] - M) * invT);
        unsigned short w2 = f2b(__expf(sc[2] - M) * invT);
        unsigned short w3 = f2b(__expf(sc[3] - M) * invT);
        unsigned long long pk = (unsigned long long)w0 | ((unsigned long long)w1 << 16)
                              | ((unsigned long long)w2 << 32) | ((unsigned long long)w3 << 48);
        *(unsigned long long*)(smem + PT + tok * 256
            + ((((rbase >> 3) ^ (tok & 7)) << 4)) + ((rbase & 7) << 1)) = pk;
        // complementary rowtile (rt+4)&7: zero (4 waves per ct cover all 8 rowtiles per token row)
        int zbase = (((rt + 4) & 7) * 16) + lhi * 4;
        *(unsigned long long*)(smem + PT + tok * 256
            + ((((zbase >> 3) ^ (tok & 7)) << 4)) + ((zbase & 7) << 1)) = 0ull;
    }
    // He_extT[f][r] <- He_hi[r][f]  (LDS transpose; chunks >9 never read -> no zero-pad needed)
    for (int e = tid; e < RE * 64; e += NT) {
        int r = e >> 6, f = e & 63;
        unsigned short h = *(const unsigned short*)
            (smem + HE_HI + r * 128 + ((((f >> 3) ^ (r & 7)) << 4)) + ((f & 7) << 1));
        *(unsigned short*)
            (smem + HET + f * 256 + ((((r >> 3) ^ (f & 7)) << 4)) + ((r & 7) << 1)) = h;
    }
    __syncthreads();

    // ---- phase 5: ctx = P^T * He_ext (banded K, hi-only, 1 tile/wave) -> global ----
    {
        int mt = wave >> 2, nt = wave & 3;
        f32x4 acc = (f32x4){0.f, 0.f, 0.f, 0.f};
        int arow = mt * 16 + l15;                           // P^T row = token
        int brow = nt * 16 + l15;                           // He^T row = f
        #pragma unroll
        for (int kk = 0; kk < 2; ++kk) {                    // K band: r_ext in [16mt, 16mt+64)
            int chunk = 2 * mt + 4 * kk + lhi;
            bf16x8 a  = *(const bf16x8*)(smem + PT  + arow * 256 + ((chunk ^ (arow & 7)) << 4));
            bf16x8 bo = *(const bf16x8*)(smem + HET + brow * 256 + ((chunk ^ (brow & 7)) << 4));
            acc = __builtin_amdgcn_mfma_f32_16x16x32_bf16(a, bo, acc, 0, 0, 0);
        }
        #pragma unroll
        for (int i = 0; i < 4; ++i) {
            int tk = mt * 16 + lhi * 4 + i;
            out[((size_t)bb * TT + t0 + tk) * FF + nt * 16 + l15] = acc[i];
        }
    }
}

extern "C" void kernel_launch(void* const* d_in, const int* in_sizes, int n_in,
                              void* d_out, int out_size, void* d_ws, size_t ws_size,
                              hipStream_t stream) {
    const float* he   = (const float*)d_in[0];
    const float* Wm   = (const float*)d_in[1];
    const float* bias = (const float*)d_in[2];
    float* out        = (float*)d_out;

    dim3 grid(TT / TB, BB);   // 64 x 8 = 512 blocks, 2 per CU
    ContextBlock_kernel<<<grid, NT, 0, stream>>>(he, Wm, bias, out);
}

// Round 5
// 11.192 us; speedup vs baseline: 1.1008x; 1.1008x over previous
//
#include <hip/hip_runtime.h>
#include <hip/hip_bf16.h>

#define BB 8
#define TT 2048
#define FF 64
#define LL 48
#define TB 64            // tokens per block
#define RE (TB + LL)     // extended He rows: t0-48 .. t0+63 (= 112)
#define NW 8
#define NT (NW * 64)

typedef __attribute__((ext_vector_type(8))) short bf16x8;   // MFMA A/B frag (8 bf16)
typedef __attribute__((ext_vector_type(4))) float f32x4;    // MFMA C/D frag

// LDS layout (bytes). HE/QQ tiles: row stride = 8 chunks * 16B, XOR-swizzle chunk ^= (row&7).
// PT: compact band [64 tok][8 chunks], local chunk = (r_ext - 16*mt)/8, swizzle c ^= (tok&7).
#define HE_HI 0          // He_ext hi [112][64] bf16 (A-op Q/S; strided B-op ctx)
#define HE_LO 14336      // He_ext lo
#define QQ_HI 28672      // Q hi [64][64] bf16 (B-op S: rows=tok, k=g)
#define QQ_LO 36864      // Q lo
#define PT    45056      // P^T banded [64][8ch] bf16 (A-op ctx: rows=tok, k=r-16mt)
#define SMEM_BYTES 53248

__device__ __forceinline__ unsigned short f2b(float x) {    // fp32 -> bf16 RNE
    unsigned int u = __builtin_bit_cast(unsigned int, x);
    return (unsigned short)((u + 0x7FFFu + ((u >> 16) & 1u)) >> 16);
}
__device__ __forceinline__ float b2f(unsigned short h) {
    return __builtin_bit_cast(float, (unsigned int)h << 16);
}

__global__ __launch_bounds__(NT, 4)
void ContextBlock_kernel(const float* __restrict__ he,
                         const float* __restrict__ Wm,
                         const float* __restrict__ bias,
                         float* __restrict__ out)
{
    __shared__ __align__(16) unsigned char smem[SMEM_BYTES];

    const int tid  = threadIdx.x;
    const int wave = tid >> 6;
    const int lane = tid & 63;
    const int bb   = blockIdx.y;
    const int t0   = blockIdx.x * TB;

    const float* heb = he + (size_t)bb * TT * FF;

    // ---- phase 1: stage He_ext hi/lo (swizzled) ----
    const float4* he4 = (const float4*)heb;
    for (int e = tid; e < RE * 16; e += NT) {               // 112 rows x 16 float4-chunks
        int r = e >> 4, c4 = e & 15;
        int g = t0 - LL + r; g = g < 0 ? 0 : g;             // clamp = reference's clip(rel,0,..)
        float4 v = he4[g * 16 + c4];
        unsigned short h0 = f2b(v.x), h1 = f2b(v.y), h2 = f2b(v.z), h3 = f2b(v.w);
        unsigned short l0 = f2b(v.x - b2f(h0)), l1 = f2b(v.y - b2f(h1));
        unsigned short l2 = f2b(v.z - b2f(h2)), l3 = f2b(v.w - b2f(h3));
        unsigned long long pkh = (unsigned long long)h0 | ((unsigned long long)h1 << 16)
                               | ((unsigned long long)h2 << 32) | ((unsigned long long)h3 << 48);
        unsigned long long pkl = (unsigned long long)l0 | ((unsigned long long)l1 << 16)
                               | ((unsigned long long)l2 << 32) | ((unsigned long long)l3 << 48);
        int off = r * 128 + ((((c4 >> 1) ^ (r & 7)) << 4)) + ((c4 & 1) << 3);
        *(unsigned long long*)(smem + HE_HI + off) = pkh;
        *(unsigned long long*)(smem + HE_LO + off) = pkl;
    }
    __syncthreads();

    const int l15 = lane & 15;
    const int lhi = lane >> 4;

    // ---- phase 2: Q = He*W + b (split-bf16; W direct from global, hi/lo in-reg) ----
    #pragma unroll
    for (int s = 0; s < 2; ++s) {
        int q = wave * 2 + s;
        int mt = q >> 2, nt = q & 3;
        f32x4 acc = (f32x4){0.f, 0.f, 0.f, 0.f};
        int arow = LL + mt * 16 + l15;                      // He row of token
        int colg = nt * 16 + l15;
        #pragma unroll
        for (int kf = 0; kf < 2; ++kf) {
            int chunk = 4 * kf + lhi;
            int offA = arow * 128 + ((chunk ^ (arow & 7)) << 4);
            bf16x8 ah = *(const bf16x8*)(smem + HE_HI + offA);
            bf16x8 al = *(const bf16x8*)(smem + HE_LO + offA);
            // B frag: element j = W[kf*32 + lhi*8 + j][colg]
            bf16x8 bh, bl;
            #pragma unroll
            for (int j = 0; j < 8; ++j) {
                float wv = Wm[(kf * 32 + lhi * 8 + j) * FF + colg];
                unsigned short hh = f2b(wv);
                bh[j] = (short)hh;
                bl[j] = (short)f2b(wv - b2f(hh));
            }
            acc = __builtin_amdgcn_mfma_f32_16x16x32_bf16(ah, bh, acc, 0, 0, 0);
            acc = __builtin_amdgcn_mfma_f32_16x16x32_bf16(ah, bl, acc, 0, 0, 0);
            acc = __builtin_amdgcn_mfma_f32_16x16x32_bf16(al, bh, acc, 0, 0, 0);
        }
        float bv = bias[colg];
        #pragma unroll
        for (int i = 0; i < 4; ++i) {                       // C: row=tok=(lane>>4)*4+i, col=g
            int tok = mt * 16 + lhi * 4 + i;
            float qv = acc[i] + bv;
            unsigned short hi = f2b(qv);
            unsigned short lo = f2b(qv - b2f(hi));
            int off = tok * 128 + ((((colg >> 3) ^ (tok & 7)) << 4)) + ((colg & 7) << 1);
            *(unsigned short*)(smem + QQ_HI + off) = hi;
            *(unsigned short*)(smem + QQ_LO + off) = lo;
        }
    }
    __syncthreads();

    // ---- phase 3: waves 0-3: full-band scores + in-wave softmax -> banded P^T ----
    if (wave < 4) {
        const int ct   = wave;                              // col-tile (16 tokens)
        const int tokc = ct * 16 + l15;                     // this lane's token column
        float sc[4][4];                                     // [u rowtile][i]
        float m = -1e30f;
        #pragma unroll
        for (int u = 0; u < 4; ++u) {
            int arow = (ct + u) * 16 + l15;                 // r_ext row of A
            f32x4 acc = (f32x4){0.f, 0.f, 0.f, 0.f};
            #pragma unroll
            for (int kf = 0; kf < 2; ++kf) {
                int chunk = 4 * kf + lhi;
                int offA = arow * 128 + ((chunk ^ (arow & 7)) << 4);
                int offB = tokc * 128 + ((chunk ^ (tokc & 7)) << 4);
                bf16x8 ah = *(const bf16x8*)(smem + HE_HI + offA);
                bf16x8 al = *(const bf16x8*)(smem + HE_LO + offA);
                bf16x8 bh = *(const bf16x8*)(smem + QQ_HI + offB);
                bf16x8 bl = *(const bf16x8*)(smem + QQ_LO + offB);
                acc = __builtin_amdgcn_mfma_f32_16x16x32_bf16(ah, bh, acc, 0, 0, 0);
                acc = __builtin_amdgcn_mfma_f32_16x16x32_bf16(ah, bl, acc, 0, 0, 0);
                acc = __builtin_amdgcn_mfma_f32_16x16x32_bf16(al, bh, acc, 0, 0, 0);
            }
            #pragma unroll
            for (int i = 0; i < 4; ++i) {
                int r_ext = (ct + u) * 16 + lhi * 4 + i;
                int l = r_ext - tokc;
                bool valid = (t0 == 0 && tokc == 0) ? (r_ext == LL - 1)
                                                    : (l >= 0 && l < LL && (t0 + r_ext) >= LL);
                float sv = valid ? acc[i] : -1e30f;
                sc[u][i] = sv;
                m = fmaxf(m, sv);
            }
        }
        m = fmaxf(m, __shfl_xor(m, 16));
        m = fmaxf(m, __shfl_xor(m, 32));                    // full column max (64 rows)
        float sum = 0.f;
        #pragma unroll
        for (int u = 0; u < 4; ++u)
            #pragma unroll
            for (int i = 0; i < 4; ++i) {
                float p = __expf(sc[u][i] - m);
                sc[u][i] = p;
                sum += p;
            }
        sum += __shfl_xor(sum, 16);
        sum += __shfl_xor(sum, 32);
        float invT = 1.0f / sum;
        #pragma unroll
        for (int u = 0; u < 4; ++u) {
            // local k = r_ext - 16*ct = 16u + 4*lhi + i -> chunk c = 2u + (lhi>>1), byte (lhi&1)*8 + i*2
            unsigned short w0 = f2b(sc[u][0] * invT);
            unsigned short w1 = f2b(sc[u][1] * invT);
            unsigned short w2 = f2b(sc[u][2] * invT);
            unsigned short w3 = f2b(sc[u][3] * invT);
            unsigned long long pk = (unsigned long long)w0 | ((unsigned long long)w1 << 16)
                                  | ((unsigned long long)w2 << 32) | ((unsigned long long)w3 << 48);
            int c = 2 * u + (lhi >> 1);
            *(unsigned long long*)(smem + PT + tokc * 128
                + ((c ^ (tokc & 7)) << 4) + ((lhi & 1) << 3)) = pk;
        }
    }
    __syncthreads();

    // ---- phase 4: ctx = P^T * He (banded K; B read strided from HE_HI) -> global ----
    #pragma unroll
    for (int s2 = 0; s2 < 2; ++s2) {
        int q = wave * 2 + s2;
        int mt = q >> 2, nt = q & 3;
        int tokrow = mt * 16 + l15;                         // A row = token
        int fcol   = nt * 16 + l15;                         // B col = f
        f32x4 acc = (f32x4){0.f, 0.f, 0.f, 0.f};
        #pragma unroll
        for (int kk = 0; kk < 2; ++kk) {
            int cA = kk * 4 + lhi;                          // local k chunk
            bf16x8 a = *(const bf16x8*)(smem + PT + tokrow * 128
                + ((cA ^ (tokrow & 7)) << 4));
            bf16x8 b;
            #pragma unroll
            for (int j = 0; j < 8; ++j) {                   // B[k][n] = He[r][f], r strided
                int r = mt * 16 + kk * 32 + lhi * 8 + j;
                b[j] = *(const short*)(smem + HE_HI + r * 128
                    + ((((fcol >> 3) ^ (r & 7)) << 4)) + ((fcol & 7) << 1));
            }
            acc = __builtin_amdgcn_mfma_f32_16x16x32_bf16(a, b, acc, 0, 0, 0);
        }
        #pragma unroll
        for (int i = 0; i < 4; ++i) {
            int tk = mt * 16 + lhi * 4 + i;
            out[((size_t)bb * TT + t0 + tk) * FF + fcol] = acc[i];
        }
    }
}

extern "C" void kernel_launch(void* const* d_in, const int* in_sizes, int n_in,
                              void* d_out, int out_size, void* d_ws, size_t ws_size,
                              hipStream_t stream) {
    const float* he   = (const float*)d_in[0];
    const float* Wm   = (const float*)d_in[1];
    const float* bias = (const float*)d_in[2];
    float* out        = (float*)d_out;

    dim3 grid(TT / TB, BB);   // 32 x 8 = 256 blocks, 2 resident/CU possible
    ContextBlock_kernel<<<grid, NT, 0, stream>>>(he, Wm, bias, out);
}